// Round 5
// baseline (24.276 us; speedup 1.0000x reference)
//
#include <hip/hip_runtime.h>
#include <math.h>

// EGES: hidden = softmax(W_weights[central]) . {item_emb, side0, mean(side1)}
//       out[b,c] = sigmoid(dot(hidden[b], W_item_out[context[b,c]]))
// B=16384, C=6, D=128.
// Layout: one wave handles FOUR rows (lane>>4 picks the row); each 16-lane
// quarter covers one 512B embedding row with float8 (2x float4) loads.
// Item-table gathers (1GB total, zero reuse) use nontemporal loads so they
// don't thrash L2/L3 and evict the resident side tables + weights (38MB).

#define D_CONST 128

typedef float f32x4 __attribute__((ext_vector_type(4)));   // native vec for nontemporal builtin

__global__ __launch_bounds__(256, 4) void eges_kernel(
    const int* __restrict__ central,       // [B]
    const int* __restrict__ side0,         // [B]
    const int* __restrict__ side1,         // [B,5]
    const int* __restrict__ ctx_items,     // [B,C]
    const float* __restrict__ W_item_in,   // [N,D]
    const float* __restrict__ W_item_out,  // [N,D]
    const float* __restrict__ W_weights,   // [N,3]
    const float* __restrict__ W_side0,     // [V0,D]
    const float* __restrict__ W_side1,     // [V1,D]
    float* __restrict__ out,               // [B,C]
    int B)
{
    const int wave = threadIdx.x >> 6;        // 4 waves/block
    const int lane = threadIdx.x & 63;
    const int q    = lane >> 4;               // which of the 4 rows this wave owns
    const int l    = lane & 15;
    const int b = blockIdx.x * 16 + wave * 4 + q;
    if (b >= B) return;

    const int d = l * 8;                      // each lane owns 8 consecutive floats

    // ---- indices ----
    const int ci  = central[b];
    const int s0i = side0[b];

    int s1idx[5];
    #pragma unroll
    for (int j = 0; j < 5; ++j) s1idx[j] = side1[b * 5 + j];

    const int2 c01 = *(const int2*)&ctx_items[b * 6 + 0];
    const int2 c23 = *(const int2*)&ctx_items[b * 6 + 2];
    const int2 c45 = *(const int2*)&ctx_items[b * 6 + 4];
    const int cidx[6] = { c01.x, c01.y, c23.x, c23.y, c45.x, c45.y };

    // ---- row gathers: 1KB per wave instruction, all independent ----
    // item tables: nontemporal (no reuse, don't pollute caches)
    const float* ip = &W_item_in[(long long)ci  * D_CONST + d];
    const f32x4 itemA = __builtin_nontemporal_load((const f32x4*)ip);
    const f32x4 itemB = __builtin_nontemporal_load((const f32x4*)(ip + 4));

    // side tables: normal (cache-resident, 0.5MB + 25.6MB)
    const f32x4 s0A = *(const f32x4*)&W_side0[(long long)s0i * D_CONST + d];
    const f32x4 s0B = *(const f32x4*)&W_side0[(long long)s0i * D_CONST + d + 4];

    f32x4 saA = (f32x4)(0.f), saB = (f32x4)(0.f);
    #pragma unroll
    for (int j = 0; j < 5; ++j) {
        const float* tp = &W_side1[(long long)s1idx[j] * D_CONST + d];
        saA += *(const f32x4*)tp;
        saB += *(const f32x4*)(tp + 4);
    }

    f32x4 oA[6], oB[6];
    #pragma unroll
    for (int c = 0; c < 6; ++c) {
        const float* op = &W_item_out[(long long)cidx[c] * D_CONST + d];
        oA[c] = __builtin_nontemporal_load((const f32x4*)op);
        oB[c] = __builtin_nontemporal_load((const f32x4*)(op + 4));
    }

    // ---- softmax over the 3 mixing weights (uniform within quarter-wave) ----
    const float* wp = &W_weights[(long long)ci * 3];
    float w0 = wp[0], w1 = wp[1], w2 = wp[2];
    const float m = fmaxf(w0, fmaxf(w1, w2));
    const float e0 = __expf(w0 - m), e1 = __expf(w1 - m), e2 = __expf(w2 - m);
    const float inv = 1.0f / (e0 + e1 + e2);
    w0 = e0 * inv; w1 = e1 * inv; w2 = e2 * inv;
    const float w2s = w2 * 0.2f;

    const f32x4 hA = w0 * itemA + w1 * s0A + w2s * saA;
    const f32x4 hB = w0 * itemB + w1 * s0B + w2s * saB;

    // ---- 6 dot products; 4-step butterfly inside the 16-lane group
    //      reduces all four of the wave's rows simultaneously ----
    #pragma unroll
    for (int c = 0; c < 6; ++c) {
        f32x4 prodA = hA * oA[c];
        f32x4 prodB = hB * oB[c];
        float p = prodA.x + prodA.y + prodA.z + prodA.w
                + prodB.x + prodB.y + prodB.z + prodB.w;
        #pragma unroll
        for (int off = 8; off >= 1; off >>= 1)
            p += __shfl_xor(p, off, 64);   // xor < 16 stays within the quarter
        if (l == 0)
            out[b * 6 + c] = 1.0f / (1.0f + __expf(-p));
    }
}

extern "C" void kernel_launch(void* const* d_in, const int* in_sizes, int n_in,
                              void* d_out, int out_size, void* d_ws, size_t ws_size,
                              hipStream_t stream) {
    const int*   central    = (const int*)d_in[0];
    const int*   side0      = (const int*)d_in[1];
    const int*   side1      = (const int*)d_in[2];
    const int*   ctx_items  = (const int*)d_in[3];
    const float* W_item_in  = (const float*)d_in[4];
    const float* W_item_out = (const float*)d_in[5];
    const float* W_weights  = (const float*)d_in[6];
    const float* W_side0    = (const float*)d_in[7];
    const float* W_side1    = (const float*)d_in[8];
    float* out = (float*)d_out;

    const int B = in_sizes[0];              // 16384
    const int blocks = (B + 15) / 16;       // 16 rows per 256-thread block (4 per wave)

    eges_kernel<<<blocks, 256, 0, stream>>>(
        central, side0, side1, ctx_items,
        W_item_in, W_item_out, W_weights, W_side0, W_side1,
        out, B);
}

// Round 6
// 22.517 us; speedup vs baseline: 1.0781x; 1.0781x over previous
//
#include <hip/hip_runtime.h>
#include <math.h>

// EGES: hidden = softmax(W_weights[central]) . {item_emb, side0, mean(side1)}
//       out[b,c] = sigmoid(dot(hidden[b], W_item_out[context[b,c]]))
// B=16384, C=6, D=128.
// Layout: one wave handles FOUR rows (lane>>4 picks the row); each 16-lane
// quarter covers one 512B embedding row with float8 (2x float4) loads.
// All gathers use normal cached loads: the per-iteration touched set (~90MB)
// fits in the 256MB Infinity Cache and is reused across graph replays —
// nontemporal loads measured 10% SLOWER (R4 experiment).

#define D_CONST 128

typedef float f32x4 __attribute__((ext_vector_type(4)));

__global__ __launch_bounds__(256, 4) void eges_kernel(
    const int* __restrict__ central,       // [B]
    const int* __restrict__ side0,         // [B]
    const int* __restrict__ side1,         // [B,5]
    const int* __restrict__ ctx_items,     // [B,C]
    const float* __restrict__ W_item_in,   // [N,D]
    const float* __restrict__ W_item_out,  // [N,D]
    const float* __restrict__ W_weights,   // [N,3]
    const float* __restrict__ W_side0,     // [V0,D]
    const float* __restrict__ W_side1,     // [V1,D]
    float* __restrict__ out,               // [B,C]
    int B)
{
    const int wave = threadIdx.x >> 6;        // 4 waves/block
    const int lane = threadIdx.x & 63;
    const int q    = lane >> 4;               // which of the 4 rows this wave owns
    const int l    = lane & 15;
    const int b = blockIdx.x * 16 + wave * 4 + q;
    if (b >= B) return;

    const int d = l * 8;                      // each lane owns 8 consecutive floats

    // ---- indices ----
    const int ci  = central[b];
    const int s0i = side0[b];

    const int4 s1a = *(const int4*)&side1[b * 5];   // side1 rows are 5 ints; 4+1
    const int  s1e = side1[b * 5 + 4];
    const int s1idx[5] = { s1a.x, s1a.y, s1a.z, s1a.w, s1e };

    const int2 c01 = *(const int2*)&ctx_items[b * 6 + 0];
    const int2 c23 = *(const int2*)&ctx_items[b * 6 + 2];
    const int2 c45 = *(const int2*)&ctx_items[b * 6 + 4];
    const int cidx[6] = { c01.x, c01.y, c23.x, c23.y, c45.x, c45.y };

    // ---- row gathers: 1KB per wave instruction, all independent ----
    const float* ip = &W_item_in[(long long)ci  * D_CONST + d];
    const f32x4 itemA = *(const f32x4*)ip;
    const f32x4 itemB = *(const f32x4*)(ip + 4);

    const float* sp = &W_side0[(long long)s0i * D_CONST + d];
    const f32x4 s0A = *(const f32x4*)sp;
    const f32x4 s0B = *(const f32x4*)(sp + 4);

    f32x4 saA = (f32x4)(0.f), saB = (f32x4)(0.f);
    #pragma unroll
    for (int j = 0; j < 5; ++j) {
        const float* tp = &W_side1[(long long)s1idx[j] * D_CONST + d];
        saA += *(const f32x4*)tp;
        saB += *(const f32x4*)(tp + 4);
    }

    f32x4 oA[6], oB[6];
    #pragma unroll
    for (int c = 0; c < 6; ++c) {
        const float* op = &W_item_out[(long long)cidx[c] * D_CONST + d];
        oA[c] = *(const f32x4*)op;
        oB[c] = *(const f32x4*)(op + 4);
    }

    // ---- softmax over the 3 mixing weights (uniform within quarter-wave) ----
    const float* wp = &W_weights[(long long)ci * 3];
    float w0 = wp[0], w1 = wp[1], w2 = wp[2];
    const float m = fmaxf(w0, fmaxf(w1, w2));
    const float e0 = __expf(w0 - m), e1 = __expf(w1 - m), e2 = __expf(w2 - m);
    const float inv = 1.0f / (e0 + e1 + e2);
    w0 = e0 * inv; w1 = e1 * inv; w2 = e2 * inv;
    const float w2s = w2 * 0.2f;

    const f32x4 hA = w0 * itemA + w1 * s0A + w2s * saA;
    const f32x4 hB = w0 * itemB + w1 * s0B + w2s * saB;

    // ---- 6 dot products; 4-step butterfly inside the 16-lane group
    //      reduces all four of the wave's rows simultaneously ----
    #pragma unroll
    for (int c = 0; c < 6; ++c) {
        f32x4 prodA = hA * oA[c];
        f32x4 prodB = hB * oB[c];
        float p = prodA.x + prodA.y + prodA.z + prodA.w
                + prodB.x + prodB.y + prodB.z + prodB.w;
        #pragma unroll
        for (int off = 8; off >= 1; off >>= 1)
            p += __shfl_xor(p, off, 64);   // xor < 16 stays within the quarter
        if (l == 0)
            out[b * 6 + c] = 1.0f / (1.0f + __expf(-p));
    }
}

extern "C" void kernel_launch(void* const* d_in, const int* in_sizes, int n_in,
                              void* d_out, int out_size, void* d_ws, size_t ws_size,
                              hipStream_t stream) {
    const int*   central    = (const int*)d_in[0];
    const int*   side0      = (const int*)d_in[1];
    const int*   side1      = (const int*)d_in[2];
    const int*   ctx_items  = (const int*)d_in[3];
    const float* W_item_in  = (const float*)d_in[4];
    const float* W_item_out = (const float*)d_in[5];
    const float* W_weights  = (const float*)d_in[6];
    const float* W_side0    = (const float*)d_in[7];
    const float* W_side1    = (const float*)d_in[8];
    float* out = (float*)d_out;

    const int B = in_sizes[0];              // 16384
    const int blocks = (B + 15) / 16;       // 16 rows per 256-thread block (4 per wave)

    eges_kernel<<<blocks, 256, 0, stream>>>(
        central, side0, side1, ctx_items,
        W_item_in, W_item_out, W_weights, W_side0, W_side1,
        out, B);
}